// Round 4
// baseline (98.717 us; speedup 1.0000x reference)
//
#include <hip/hip_runtime.h>
#include <hip/hip_bf16.h>
#include <math.h>

#define N_ROWS 8192
#define N_HALF 4096
#define D 128
#define IT_ROWS 64
#define IBLKS (N_ROWS / IT_ROWS)        // 128
#define SEGS 8
#define SEGROWS (N_ROWS / SEGS)         // 1024
#define ITERS ((SEGROWS / 128) * 2)     // 16  (8 chunks x 2 col-halves)
// scale = sqrt(2 * log2(e)) so that zb_i . zb_j = 2*log2(e)*cos -> exp2(dot) = exp(2*cos)
#define ZSCALE 1.6986437717f
#define LN2 0.69314718056f

typedef __attribute__((ext_vector_type(8))) short bfrag;   // 8 bf16 = 4 VGPR
typedef __attribute__((ext_vector_type(4))) float f32x4;

__device__ __forceinline__ float fast_exp2(float x) {
#if __has_builtin(__builtin_amdgcn_exp2f)
    return __builtin_amdgcn_exp2f(x);
#else
    return exp2f(x);
#endif
}

// ---------------- kernel 1: normalize rows; emit scaled bf16 z ----------------
__global__ __launch_bounds__(256) void normalize_kernel(
    const float* __restrict__ p1, const float* __restrict__ p2,
    ushort* __restrict__ zb)
{
    const int row = blockIdx.x * 4 + (threadIdx.x >> 6);
    const int lane = threadIdx.x & 63;
    const float* src = (row < N_HALF) ? (p1 + (size_t)row * D)
                                      : (p2 + (size_t)(row - N_HALF) * D);
    float2 v = ((const float2*)src)[lane];
    float ss = v.x * v.x + v.y * v.y;
    #pragma unroll
    for (int m = 1; m < 64; m <<= 1) ss += __shfl_xor(ss, m);
    float inv = ZSCALE / fmaxf(sqrtf(ss), 1e-12f);
    __hip_bfloat16 h0 = __float2bfloat16(v.x * inv);
    __hip_bfloat16 h1 = __float2bfloat16(v.y * inv);
    ushort2 u; u.x = *(ushort*)&h0; u.y = *(ushort*)&h1;
    ((ushort2*)(zb + (size_t)row * D))[lane] = u;
}

// ---------------- kernel 2: prefetched MFMA Gram + exp2 row-sums + positives ----------------
__global__ __launch_bounds__(256, 3) void simloss_mfma(
    const ushort* __restrict__ zb, float* __restrict__ partial,
    float* __restrict__ posv)
{
    __shared__ float red[IT_ROWS][4];   // epilogue only
    const int t = threadIdx.x;
    const int w = t >> 6;               // wave 0..3
    const int l = t & 63;
    const int l15 = l & 15, lh = l >> 4;
    const int bi = blockIdx.x & (IBLKS - 1);
    const int seg = blockIdx.x >> 7;
    const int iBase = bi * IT_ROWS;
    const int segBase = seg * SEGROWS;

    const int pd = iBase ^ N_HALF;      // partner row base
    const int pdChunk = pd & ~127;      // chunk (global row base) holding partner diag
    const int pdOff = pd & 64;
    const int sdChunk = iBase & ~127;
    const int sdOff = iBase & 64;

    // A tile (64 rows x 128 k) in registers (L2-resident source)
    bfrag a[4][4];
    #pragma unroll
    for (int m = 0; m < 4; ++m) {
        const ushort* rp = zb + (size_t)(iBase + m * 16 + l15) * D;
        #pragma unroll
        for (int ks = 0; ks < 4; ++ks)
            a[m][ks] = *(const bfrag*)(rp + ks * 32 + lh * 8);
    }

    float rs[4][4];
    #pragma unroll
    for (int m = 0; m < 4; ++m)
        #pragma unroll
        for (int r = 0; r < 4; ++r) rs[m][r] = 0.0f;

    const int colLane = w * 32 + l15;   // col within chunk when n==0

#define BPTR(it) (zb + (size_t)(segBase + ((it) >> 1) * 128 + colLane + ((it) & 1) * 16) * D + lh * 8)

    const ushort* p0 = BPTR(0);
    bfrag nb0 = *(const bfrag*)(p0);
    bfrag nb1 = *(const bfrag*)(p0 + 32);
    bfrag nb2 = *(const bfrag*)(p0 + 64);
    bfrag nb3 = *(const bfrag*)(p0 + 96);

    #pragma unroll
    for (int it = 0; it < ITERS; ++it) {
        bfrag b0 = nb0, b1 = nb1, b2 = nb2, b3 = nb3;
        if (it + 1 < ITERS) {           // prefetch next iteration's B frags
            const ushort* p = BPTR(it + 1);
            nb0 = *(const bfrag*)(p);
            nb1 = *(const bfrag*)(p + 32);
            nb2 = *(const bfrag*)(p + 64);
            nb3 = *(const bfrag*)(p + 96);
        }

        f32x4 c[4];
        #pragma unroll
        for (int m = 0; m < 4; ++m) { f32x4 z4 = {0.f, 0.f, 0.f, 0.f}; c[m] = z4; }
        #pragma unroll
        for (int m = 0; m < 4; ++m)
            c[m] = __builtin_amdgcn_mfma_f32_16x16x32_bf16(a[m][0], b0, c[m], 0, 0, 0);
        #pragma unroll
        for (int m = 0; m < 4; ++m)
            c[m] = __builtin_amdgcn_mfma_f32_16x16x32_bf16(a[m][1], b1, c[m], 0, 0, 0);
        #pragma unroll
        for (int m = 0; m < 4; ++m)
            c[m] = __builtin_amdgcn_mfma_f32_16x16x32_bf16(a[m][2], b2, c[m], 0, 0, 0);
        #pragma unroll
        for (int m = 0; m < 4; ++m)
            c[m] = __builtin_amdgcn_mfma_f32_16x16x32_bf16(a[m][3], b3, c[m], 0, 0, 0);

        const int jBase = segBase + (it >> 1) * 128;
        const int cB = colLane + (it & 1) * 16;

        if (jBase == sdChunk) {         // rare: chunk containing self-diagonal
            #pragma unroll
            for (int m = 0; m < 4; ++m)
                #pragma unroll
                for (int r = 0; r < 4; ++r) {
                    const int rowLocal = m * 16 + lh * 4 + r;
                    float e = fast_exp2(c[m][r]);
                    rs[m][r] += (cB == sdOff + rowLocal) ? 0.0f : e;
                }
        } else {                        // hot path: no per-element guard
            #pragma unroll
            for (int m = 0; m < 4; ++m)
                #pragma unroll
                for (int r = 0; r < 4; ++r)
                    rs[m][r] += fast_exp2(c[m][r]);
        }
        if (jBase == pdChunk) {         // rare: chunk containing partner diagonal
            #pragma unroll
            for (int m = 0; m < 4; ++m)
                #pragma unroll
                for (int r = 0; r < 4; ++r) {
                    const int rowLocal = m * 16 + lh * 4 + r;
                    if (cB == pdOff + rowLocal)
                        posv[iBase + rowLocal] = c[m][r] * LN2;   // = 2*cos
                }
        }
    }
#undef BPTR

    // reduce rs over the 16 cols held across l15 lanes
    #pragma unroll
    for (int m = 0; m < 4; ++m)
        #pragma unroll
        for (int r = 0; r < 4; ++r) {
            float v = rs[m][r];
            v += __shfl_xor(v, 1); v += __shfl_xor(v, 2);
            v += __shfl_xor(v, 4); v += __shfl_xor(v, 8);
            rs[m][r] = v;
        }
    if (l15 == 0) {
        #pragma unroll
        for (int m = 0; m < 4; ++m)
            #pragma unroll
            for (int r = 0; r < 4; ++r)
                red[m * 16 + lh * 4 + r][w] = rs[m][r];
    }
    __syncthreads();
    if (t < IT_ROWS) {
        float v = red[t][0] + red[t][1] + red[t][2] + red[t][3];
        partial[(size_t)seg * N_ROWS + iBase + t] = v;
    }
}

// ---------------- kernel 3: per-row loss + per-block deterministic sum ----------------
__global__ __launch_bounds__(256) void rowloss_kernel(
    const float* __restrict__ partial, const float* __restrict__ posv,
    float* __restrict__ bsum)
{
    const int row = blockIdx.x * 256 + threadIdx.x;
    float denom = 0.0f;
    #pragma unroll
    for (int s = 0; s < SEGS; ++s) denom += partial[(size_t)s * N_ROWS + row];
    float loss = logf(denom) - posv[row];
    #pragma unroll
    for (int m = 1; m < 64; m <<= 1) loss += __shfl_xor(loss, m);
    __shared__ float red[4];
    if ((threadIdx.x & 63) == 0) red[threadIdx.x >> 6] = loss;
    __syncthreads();
    if (threadIdx.x == 0) bsum[blockIdx.x] = red[0] + red[1] + red[2] + red[3];
}

// ---------------- kernel 4: final deterministic reduce of 32 block sums ----------------
__global__ __launch_bounds__(64) void final_reduce(
    const float* __restrict__ bsum, float* __restrict__ out)
{
    const int t = threadIdx.x;
    float s = (t < 32) ? bsum[t] : 0.0f;
    #pragma unroll
    for (int m = 1; m < 64; m <<= 1) s += __shfl_xor(s, m);
    if (t == 0) out[0] = s * (1.0f / (float)N_ROWS);
}

extern "C" void kernel_launch(void* const* d_in, const int* in_sizes, int n_in,
                              void* d_out, int out_size, void* d_ws, size_t ws_size,
                              hipStream_t stream) {
    const float* proj1 = (const float*)d_in[0];
    const float* proj2 = (const float*)d_in[1];
    float* out = (float*)d_out;

    char* ws = (char*)d_ws;
    ushort* zb      = (ushort*)ws;                                  // 2 MB
    float*  partial = (float*)(ws + (size_t)2 * 1024 * 1024);       // 256 KB
    float*  posv    = (float*)(ws + (size_t)2 * 1024 * 1024 + 512 * 1024);  // 32 KB
    float*  bsum    = (float*)(ws + (size_t)2 * 1024 * 1024 + 768 * 1024);  // 128 B

    normalize_kernel<<<N_ROWS / 4, 256, 0, stream>>>(proj1, proj2, zb);
    simloss_mfma<<<IBLKS * SEGS, 256, 0, stream>>>(zb, partial, posv);
    rowloss_kernel<<<N_ROWS / 256, 256, 0, stream>>>(partial, posv, bsum);
    final_reduce<<<1, 64, 0, stream>>>(bsum, out);
}

// Round 5
// 65.565 us; speedup vs baseline: 1.5056x; 1.5056x over previous
//
#include <hip/hip_runtime.h>
#include <hip/hip_bf16.h>
#include <math.h>

#define N_ROWS 8192
#define N_HALF 4096
#define D 128
#define SEGS 8
#define IBLKS (N_ROWS / 128)            // 64 i-tiles
#define SEGROWS (N_ROWS / SEGS)         // 1024
#define CHUNKS (SEGROWS / 128)          // 8 chunks per segment
// scale = sqrt(2 * log2(e)): zb_i . zb_j = 2*log2(e)*cos -> exp2(dot) = exp(2*cos)
#define ZSCALE 1.6986437717f
#define LN2 0.69314718056f

typedef __attribute__((ext_vector_type(8))) short bfrag;   // 8 bf16 = 4 VGPR
typedef __attribute__((ext_vector_type(4))) float f32x4;

__device__ __forceinline__ float fast_exp2(float x) {
#if __has_builtin(__builtin_amdgcn_exp2f)
    return __builtin_amdgcn_exp2f(x);
#else
    return exp2f(x);
#endif
}

// ---------------- kernel 1: normalize rows; emit scaled bf16 z ----------------
__global__ __launch_bounds__(256) void normalize_kernel(
    const float* __restrict__ p1, const float* __restrict__ p2,
    ushort* __restrict__ zb)
{
    const int row = blockIdx.x * 4 + (threadIdx.x >> 6);
    const int lane = threadIdx.x & 63;
    const float* src = (row < N_HALF) ? (p1 + (size_t)row * D)
                                      : (p2 + (size_t)(row - N_HALF) * D);
    float2 v = ((const float2*)src)[lane];
    float ss = v.x * v.x + v.y * v.y;
    #pragma unroll
    for (int m = 1; m < 64; m <<= 1) ss += __shfl_xor(ss, m);
    float inv = ZSCALE / fmaxf(sqrtf(ss), 1e-12f);
    __hip_bfloat16 h0 = __float2bfloat16(v.x * inv);
    __hip_bfloat16 h1 = __float2bfloat16(v.y * inv);
    ushort2 u; u.x = *(ushort*)&h0; u.y = *(ushort*)&h1;
    ((ushort2*)(zb + (size_t)row * D))[lane] = u;
}

// ---------------- kernel 2: dbuf-DMA MFMA Gram + exp2 row-sums + positives ----------------
// LDS layout: linear 16B slot s holds global element (r = s>>4, c16 = (s&15)^(r&7)).
// Read for (col cB, k16): slot = cB*16 + (k16 ^ (cB&7))  -> conflict-free ds_read_b128.
__global__ __launch_bounds__(256, 2) void simloss_mfma(
    const ushort* __restrict__ zb, float* __restrict__ partial,
    float* __restrict__ posv)
{
    __shared__ ushort Bs[2][128 * 128];   // 2 x 32 KB
    __shared__ float red[128][4];
    const int t = threadIdx.x;
    const int w = t >> 6;                 // wave 0..3
    const int l = t & 63;
    const int l15 = l & 15, lh = l >> 4;
    const int bi = blockIdx.x & (IBLKS - 1);
    const int seg = blockIdx.x >> 6;
    const int iBase = bi * 128;
    const int segBase = seg * SEGROWS;
    const int pdChunk = iBase ^ N_HALF;   // 128-aligned partner tile base

// stage one 128x128 chunk into buf: 8 DMA issues per wave, wave-linear LDS,
// per-lane inverse-swizzled global source (rule #21: both-sides-or-neither).
#define STAGE(buf, jB)                                                          \
    {                                                                           \
        _Pragma("unroll")                                                       \
        for (int i = 0; i < 8; ++i) {                                           \
            const int s = w * 512 + i * 64 + l;                                 \
            const int r = s >> 4;                                               \
            const int c = (s & 15) ^ (r & 7);                                   \
            const ushort* g = zb + (size_t)((jB) + r) * D + c * 8;              \
            ushort* lp = (buf) + (size_t)(w * 512 + i * 64) * 8;                \
            __builtin_amdgcn_global_load_lds(                                   \
                (const __attribute__((address_space(1))) unsigned int*)g,       \
                (__attribute__((address_space(3))) unsigned int*)lp, 16, 0, 0); \
        }                                                                       \
    }

    // A tile (128 rows x 128 k) in registers (L2-resident source)
    bfrag a[8][4];
    #pragma unroll
    for (int m = 0; m < 8; ++m) {
        const ushort* rp = zb + (size_t)(iBase + m * 16 + l15) * D;
        #pragma unroll
        for (int ks = 0; ks < 4; ++ks)
            a[m][ks] = *(const bfrag*)(rp + ks * 32 + lh * 8);
    }

    STAGE(&Bs[0][0], segBase);            // prologue: chunk 0 in flight

    float rs[8][4];
    #pragma unroll
    for (int m = 0; m < 8; ++m)
        #pragma unroll
        for (int r = 0; r < 4; ++r) rs[m][r] = 0.0f;

    #pragma unroll 1
    for (int ch = 0; ch < CHUNKS; ++ch) {
        const int jBase = segBase + ch * 128;
        const ushort* bufc = &Bs[ch & 1][0];

        if (ch + 1 < CHUNKS) {
            STAGE(&Bs[(ch & 1) ^ 1][0], jBase + 128);   // prefetch next chunk
            asm volatile("s_waitcnt vmcnt(8)" ::: "memory");  // current chunk landed
        } else {
            asm volatile("s_waitcnt vmcnt(0)" ::: "memory");
        }
        __builtin_amdgcn_s_barrier();
        asm volatile("" ::: "memory");

        const bool sdiag = (jBase == iBase);
        const bool pdiag = (jBase == pdChunk);

        #pragma unroll
        for (int n = 0; n < 2; ++n) {
            const int cB = w * 32 + n * 16 + l15;
            bfrag b[4];
            #pragma unroll
            for (int ks = 0; ks < 4; ++ks) {
                const int k16 = ks * 4 + lh;
                const int slot = cB * 16 + (k16 ^ (cB & 7));
                b[ks] = *(const bfrag*)(bufc + slot * 8);
            }
            f32x4 c[8];
            #pragma unroll
            for (int m = 0; m < 8; ++m) { f32x4 z4 = {0.f, 0.f, 0.f, 0.f}; c[m] = z4; }
            #pragma unroll
            for (int ks = 0; ks < 4; ++ks)
                #pragma unroll
                for (int m = 0; m < 8; ++m)
                    c[m] = __builtin_amdgcn_mfma_f32_16x16x32_bf16(a[m][ks], b[ks], c[m], 0, 0, 0);

            if (sdiag) {                  // rare: chunk containing self-diagonal
                #pragma unroll
                for (int m = 0; m < 8; ++m)
                    #pragma unroll
                    for (int r = 0; r < 4; ++r) {
                        const int rowLocal = m * 16 + lh * 4 + r;
                        float e = fast_exp2(c[m][r]);
                        rs[m][r] += (cB == rowLocal) ? 0.0f : e;
                    }
            } else {                      // hot path: no per-element guard
                #pragma unroll
                for (int m = 0; m < 8; ++m)
                    #pragma unroll
                    for (int r = 0; r < 4; ++r)
                        rs[m][r] += fast_exp2(c[m][r]);
            }
            if (pdiag) {                  // rare: chunk containing partner diagonal
                #pragma unroll
                for (int m = 0; m < 8; ++m)
                    #pragma unroll
                    for (int r = 0; r < 4; ++r) {
                        const int rowLocal = m * 16 + lh * 4 + r;
                        if (cB == rowLocal)
                            posv[iBase + rowLocal] = c[m][r] * LN2;   // = 2*cos
                    }
            }
        }

        asm volatile("" ::: "memory");
        __builtin_amdgcn_s_barrier();     // all waves done reading buf before re-stage
        asm volatile("" ::: "memory");
    }
#undef STAGE

    // reduce rs over the 16 cols held across l15 lanes
    #pragma unroll
    for (int m = 0; m < 8; ++m)
        #pragma unroll
        for (int r = 0; r < 4; ++r) {
            float v = rs[m][r];
            v += __shfl_xor(v, 1); v += __shfl_xor(v, 2);
            v += __shfl_xor(v, 4); v += __shfl_xor(v, 8);
            rs[m][r] = v;
        }
    if (l15 == 0) {
        #pragma unroll
        for (int m = 0; m < 8; ++m)
            #pragma unroll
            for (int r = 0; r < 4; ++r)
                red[m * 16 + lh * 4 + r][w] = rs[m][r];
    }
    __syncthreads();
    if (t < 128) {
        float v = red[t][0] + red[t][1] + red[t][2] + red[t][3];
        partial[(size_t)seg * N_ROWS + iBase + t] = v;
    }
}

// ---------------- kernel 3: per-row loss + per-block deterministic sum ----------------
__global__ __launch_bounds__(256) void rowloss_kernel(
    const float* __restrict__ partial, const float* __restrict__ posv,
    float* __restrict__ bsum)
{
    const int row = blockIdx.x * 256 + threadIdx.x;
    float denom = 0.0f;
    #pragma unroll
    for (int s = 0; s < SEGS; ++s) denom += partial[(size_t)s * N_ROWS + row];
    float loss = logf(denom) - posv[row];
    #pragma unroll
    for (int m = 1; m < 64; m <<= 1) loss += __shfl_xor(loss, m);
    __shared__ float red[4];
    if ((threadIdx.x & 63) == 0) red[threadIdx.x >> 6] = loss;
    __syncthreads();
    if (threadIdx.x == 0) bsum[blockIdx.x] = red[0] + red[1] + red[2] + red[3];
}

// ---------------- kernel 4: final deterministic reduce of 32 block sums ----------------
__global__ __launch_bounds__(64) void final_reduce(
    const float* __restrict__ bsum, float* __restrict__ out)
{
    const int t = threadIdx.x;
    float s = (t < 32) ? bsum[t] : 0.0f;
    #pragma unroll
    for (int m = 1; m < 64; m <<= 1) s += __shfl_xor(s, m);
    if (t == 0) out[0] = s * (1.0f / (float)N_ROWS);
}

extern "C" void kernel_launch(void* const* d_in, const int* in_sizes, int n_in,
                              void* d_out, int out_size, void* d_ws, size_t ws_size,
                              hipStream_t stream) {
    const float* proj1 = (const float*)d_in[0];
    const float* proj2 = (const float*)d_in[1];
    float* out = (float*)d_out;

    char* ws = (char*)d_ws;
    ushort* zb      = (ushort*)ws;                                  // 2 MB
    float*  partial = (float*)(ws + (size_t)2 * 1024 * 1024);       // 256 KB
    float*  posv    = (float*)(ws + (size_t)2 * 1024 * 1024 + 512 * 1024);  // 32 KB
    float*  bsum    = (float*)(ws + (size_t)2 * 1024 * 1024 + 768 * 1024);  // 128 B

    normalize_kernel<<<N_ROWS / 4, 256, 0, stream>>>(proj1, proj2, zb);
    simloss_mfma<<<IBLKS * SEGS, 256, 0, stream>>>(zb, partial, posv);
    rowloss_kernel<<<N_ROWS / 256, 256, 0, stream>>>(partial, posv, bsum);
    final_reduce<<<1, 64, 0, stream>>>(bsum, out);
}

// Round 6
// 63.034 us; speedup vs baseline: 1.5661x; 1.0402x over previous
//
#include <hip/hip_runtime.h>
#include <hip/hip_bf16.h>
#include <math.h>

#define N_ROWS 8192
#define N_HALF 4096
#define D 128
#define IT_ROWS 64
#define IBLKS (N_ROWS / IT_ROWS)        // 128 i-tiles
#define SEGS 16
#define SEGROWS (N_ROWS / SEGS)         // 512 cols per block
#define WAVE_COLS (SEGROWS / 4)         // 128 cols per wave
#define WITERS (WAVE_COLS / 16)         // 8 iterations per wave
// scale = sqrt(2 * log2(e)): zb_i . zb_j = 2*log2(e)*cos -> exp2(dot) = exp(2*cos)
#define ZSCALE 1.6986437717f
#define LN2 0.69314718056f

typedef __attribute__((ext_vector_type(8))) short bfrag;   // 8 bf16 = 4 VGPR
typedef __attribute__((ext_vector_type(4))) float f32x4;

__device__ __forceinline__ float fast_exp2(float x) {
#if __has_builtin(__builtin_amdgcn_exp2f)
    return __builtin_amdgcn_exp2f(x);
#else
    return exp2f(x);
#endif
}

// ---------------- kernel 1: normalize rows; emit scaled bf16 z ----------------
__global__ __launch_bounds__(256) void normalize_kernel(
    const float* __restrict__ p1, const float* __restrict__ p2,
    ushort* __restrict__ zb)
{
    const int row = blockIdx.x * 4 + (threadIdx.x >> 6);
    const int lane = threadIdx.x & 63;
    const float* src = (row < N_HALF) ? (p1 + (size_t)row * D)
                                      : (p2 + (size_t)(row - N_HALF) * D);
    float2 v = ((const float2*)src)[lane];
    float ss = v.x * v.x + v.y * v.y;
    #pragma unroll
    for (int m = 1; m < 64; m <<= 1) ss += __shfl_xor(ss, m);
    float inv = ZSCALE / fmaxf(sqrtf(ss), 1e-12f);
    __hip_bfloat16 h0 = __float2bfloat16(v.x * inv);
    __hip_bfloat16 h1 = __float2bfloat16(v.y * inv);
    ushort2 u; u.x = *(ushort*)&h0; u.y = *(ushort*)&h1;
    ((ushort2*)(zb + (size_t)row * D))[lane] = u;
}

// ---------------- kernel 2: barrier-free MFMA Gram + exp2 row-sums + positives ----------------
__global__ __launch_bounds__(256, 3) void simloss_mfma(
    const ushort* __restrict__ zb, float* __restrict__ partial,
    float* __restrict__ posv)
{
    __shared__ float red[IT_ROWS][4];   // epilogue only
    const int t = threadIdx.x;
    const int w = t >> 6;               // wave 0..3 -> 128-col slice of segment
    const int l = t & 63;
    const int l15 = l & 15, lh = l >> 4;
    const int bi = blockIdx.x & (IBLKS - 1);
    const int seg = blockIdx.x >> 7;
    const int iBase = bi * IT_ROWS;     // 64-aligned
    const int pBase = iBase ^ N_HALF;   // partner-diag col base (64-aligned)
    const int wBase = seg * SEGROWS + w * WAVE_COLS;   // this wave's first col

    // A tile (64 rows x 128 k) in registers (L2-resident source)
    bfrag a[4][4];
    #pragma unroll
    for (int m = 0; m < 4; ++m) {
        const ushort* rp = zb + (size_t)(iBase + m * 16 + l15) * D;
        #pragma unroll
        for (int ks = 0; ks < 4; ++ks)
            a[m][ks] = *(const bfrag*)(rp + ks * 32 + lh * 8);
    }

    float rs[4][4];
    #pragma unroll
    for (int m = 0; m < 4; ++m)
        #pragma unroll
        for (int r = 0; r < 4; ++r) rs[m][r] = 0.0f;

    // prologue: prefetch iteration 0's B frags (lane owns col wBase + l15)
    const ushort* p0 = zb + (size_t)(wBase + l15) * D + lh * 8;
    bfrag nb0 = *(const bfrag*)(p0);
    bfrag nb1 = *(const bfrag*)(p0 + 32);
    bfrag nb2 = *(const bfrag*)(p0 + 64);
    bfrag nb3 = *(const bfrag*)(p0 + 96);

    #pragma unroll 1
    for (int it = 0; it < WITERS; ++it) {
        bfrag b0 = nb0, b1 = nb1, b2 = nb2, b3 = nb3;
        if (it + 1 < WITERS) {          // 1-deep prefetch of next 16 cols
            const ushort* p = zb + (size_t)(wBase + (it + 1) * 16 + l15) * D + lh * 8;
            nb0 = *(const bfrag*)(p);
            nb1 = *(const bfrag*)(p + 32);
            nb2 = *(const bfrag*)(p + 64);
            nb3 = *(const bfrag*)(p + 96);
        }

        f32x4 c[4];
        #pragma unroll
        for (int m = 0; m < 4; ++m) { f32x4 z4 = {0.f, 0.f, 0.f, 0.f}; c[m] = z4; }
        #pragma unroll
        for (int m = 0; m < 4; ++m)
            c[m] = __builtin_amdgcn_mfma_f32_16x16x32_bf16(a[m][0], b0, c[m], 0, 0, 0);
        #pragma unroll
        for (int m = 0; m < 4; ++m)
            c[m] = __builtin_amdgcn_mfma_f32_16x16x32_bf16(a[m][1], b1, c[m], 0, 0, 0);
        #pragma unroll
        for (int m = 0; m < 4; ++m)
            c[m] = __builtin_amdgcn_mfma_f32_16x16x32_bf16(a[m][2], b2, c[m], 0, 0, 0);
        #pragma unroll
        for (int m = 0; m < 4; ++m)
            c[m] = __builtin_amdgcn_mfma_f32_16x16x32_bf16(a[m][3], b3, c[m], 0, 0, 0);

        const int j0 = wBase + it * 16;          // global col base this iter

        if ((j0 & ~63) == iBase) {               // rare: covers self-diagonal
            const int sOff = j0 - iBase;         // 0,16,32,48
            #pragma unroll
            for (int m = 0; m < 4; ++m)
                #pragma unroll
                for (int r = 0; r < 4; ++r) {
                    const int rowLocal = m * 16 + lh * 4 + r;
                    float e = fast_exp2(c[m][r]);
                    rs[m][r] += (rowLocal == sOff + l15) ? 0.0f : e;
                }
        } else {                                  // hot path
            #pragma unroll
            for (int m = 0; m < 4; ++m)
                #pragma unroll
                for (int r = 0; r < 4; ++r)
                    rs[m][r] += fast_exp2(c[m][r]);
        }
        if ((j0 & ~63) == pBase) {               // rare: covers partner diagonal
            const int pOff = j0 - pBase;         // 0,16,32,48
            #pragma unroll
            for (int m = 0; m < 4; ++m)
                #pragma unroll
                for (int r = 0; r < 4; ++r) {
                    const int rowLocal = m * 16 + lh * 4 + r;
                    if (rowLocal == pOff + l15)
                        posv[iBase + rowLocal] = c[m][r] * LN2;   // = 2*cos
                }
        }
    }

    // reduce rs over the 16 cols held across l15 lanes
    #pragma unroll
    for (int m = 0; m < 4; ++m)
        #pragma unroll
        for (int r = 0; r < 4; ++r) {
            float v = rs[m][r];
            v += __shfl_xor(v, 1); v += __shfl_xor(v, 2);
            v += __shfl_xor(v, 4); v += __shfl_xor(v, 8);
            rs[m][r] = v;
        }
    if (l15 == 0) {
        #pragma unroll
        for (int m = 0; m < 4; ++m)
            #pragma unroll
            for (int r = 0; r < 4; ++r)
                red[m * 16 + lh * 4 + r][w] = rs[m][r];
    }
    __syncthreads();
    if (t < IT_ROWS) {
        float v = red[t][0] + red[t][1] + red[t][2] + red[t][3];
        partial[(size_t)seg * N_ROWS + iBase + t] = v;
    }
}

// ---------------- kernel 3: per-row loss + per-block deterministic sum ----------------
__global__ __launch_bounds__(256) void rowloss_kernel(
    const float* __restrict__ partial, const float* __restrict__ posv,
    float* __restrict__ bsum)
{
    const int row = blockIdx.x * 256 + threadIdx.x;
    float denom = 0.0f;
    #pragma unroll
    for (int s = 0; s < SEGS; ++s) denom += partial[(size_t)s * N_ROWS + row];
    float loss = logf(denom) - posv[row];
    #pragma unroll
    for (int m = 1; m < 64; m <<= 1) loss += __shfl_xor(loss, m);
    __shared__ float red[4];
    if ((threadIdx.x & 63) == 0) red[threadIdx.x >> 6] = loss;
    __syncthreads();
    if (threadIdx.x == 0) bsum[blockIdx.x] = red[0] + red[1] + red[2] + red[3];
}

// ---------------- kernel 4: final deterministic reduce of 32 block sums ----------------
__global__ __launch_bounds__(64) void final_reduce(
    const float* __restrict__ bsum, float* __restrict__ out)
{
    const int t = threadIdx.x;
    float s = (t < 32) ? bsum[t] : 0.0f;
    #pragma unroll
    for (int m = 1; m < 64; m <<= 1) s += __shfl_xor(s, m);
    if (t == 0) out[0] = s * (1.0f / (float)N_ROWS);
}

extern "C" void kernel_launch(void* const* d_in, const int* in_sizes, int n_in,
                              void* d_out, int out_size, void* d_ws, size_t ws_size,
                              hipStream_t stream) {
    const float* proj1 = (const float*)d_in[0];
    const float* proj2 = (const float*)d_in[1];
    float* out = (float*)d_out;

    char* ws = (char*)d_ws;
    ushort* zb      = (ushort*)ws;                                      // 2 MB
    float*  partial = (float*)(ws + (size_t)2 * 1024 * 1024);           // 512 KB (16 segs)
    float*  posv    = (float*)(ws + (size_t)2 * 1024 * 1024 + 768 * 1024);   // 32 KB
    float*  bsum    = (float*)(ws + (size_t)2 * 1024 * 1024 + 896 * 1024);   // 128 B

    normalize_kernel<<<N_ROWS / 4, 256, 0, stream>>>(proj1, proj2, zb);
    simloss_mfma<<<IBLKS * SEGS, 256, 0, stream>>>(zb, partial, posv);
    rowloss_kernel<<<N_ROWS / 256, 256, 0, stream>>>(partial, posv, bsum);
    final_reduce<<<1, 64, 0, stream>>>(bsum, out);
}

// Round 7
// 40.074 us; speedup vs baseline: 2.4634x; 1.5729x over previous
//
#include <hip/hip_runtime.h>
#include <hip/hip_bf16.h>
#include <math.h>

#define N_ROWS 8192
#define N_HALF 4096
#define D 128
#define SEGS 8
#define IBLKS (N_ROWS / 128)            // 64 i-tiles of 128 rows
#define SEGCOLS (N_ROWS / SEGS)         // 1024 cols per block
#define HALVES (SEGCOLS / 64)           // 16 halves of 64 cols
// scale = sqrt(2 * log2(e)): zb_i . zb_j = 2*log2(e)*cos -> exp2(dot) = exp(2*cos)
#define ZSCALE 1.6986437717f
#define LN2 0.69314718056f

typedef __attribute__((ext_vector_type(8))) short bfrag;   // 8 bf16 = 4 VGPR
typedef __attribute__((ext_vector_type(4))) float f32x4;

__device__ __forceinline__ float fast_exp2(float x) {
#if __has_builtin(__builtin_amdgcn_exp2f)
    return __builtin_amdgcn_exp2f(x);
#else
    return exp2f(x);
#endif
}

// ---------------- kernel 1: normalize rows; emit scaled bf16 z ----------------
__global__ __launch_bounds__(256) void normalize_kernel(
    const float* __restrict__ p1, const float* __restrict__ p2,
    ushort* __restrict__ zb)
{
    const int row = blockIdx.x * 4 + (threadIdx.x >> 6);
    const int lane = threadIdx.x & 63;
    const float* src = (row < N_HALF) ? (p1 + (size_t)row * D)
                                      : (p2 + (size_t)(row - N_HALF) * D);
    float2 v = ((const float2*)src)[lane];
    float ss = v.x * v.x + v.y * v.y;
    #pragma unroll
    for (int m = 1; m < 64; m <<= 1) ss += __shfl_xor(ss, m);
    float inv = ZSCALE / fmaxf(sqrtf(ss), 1e-12f);
    __hip_bfloat16 h0 = __float2bfloat16(v.x * inv);
    __hip_bfloat16 h1 = __float2bfloat16(v.y * inv);
    ushort2 u; u.x = *(ushort*)&h0; u.y = *(ushort*)&h1;
    ((ushort2*)(zb + (size_t)row * D))[lane] = u;
}

// ---------------- kernel 2: half-chunk dbuf DMA + MFMA Gram + exp2 row-sums ----------------
// LDS half-buffer: 1024 slots of 16B. Slot s holds global (r = s>>4, c16 = (s&15)^(r&7)).
// Read (col cB, k16): slot = cB*16 + (k16 ^ (cB&7)) -> 2-way-max bank aliasing (free).
__global__ __launch_bounds__(256, 2) void simloss_mfma(
    const ushort* __restrict__ zb, float* __restrict__ partial,
    float* __restrict__ posv)
{
    __shared__ ushort Bs[2][64 * 128];   // 2 x 16 KB
    __shared__ float red[128][4];
    const int t = threadIdx.x;
    const int w = t >> 6;                // wave 0..3 -> 16-col slice of the 64-col half
    const int l = t & 63;
    const int l15 = l & 15, lh = l >> 4;
    const int bi = blockIdx.x & (IBLKS - 1);
    const int seg = blockIdx.x >> 6;
    const int iBase = bi * 128;
    const int segBase = seg * SEGCOLS;
    const int pBase = iBase ^ N_HALF;    // partner tile base (128-aligned)

// stage one 64x128 half into buf: 4 DMA issues per wave, wave-linear LDS dest,
// per-lane inverse-swizzled global source (rule #21).
#define STAGE(buf, jB)                                                          \
    {                                                                           \
        _Pragma("unroll")                                                       \
        for (int i = 0; i < 4; ++i) {                                           \
            const int s = w * 256 + i * 64 + l;                                 \
            const int r = s >> 4;                                               \
            const int c = (s & 15) ^ (r & 7);                                   \
            const ushort* g = zb + (size_t)((jB) + r) * D + c * 8;              \
            ushort* lp = (buf) + (size_t)s * 8;                                 \
            __builtin_amdgcn_global_load_lds(                                   \
                (const __attribute__((address_space(1))) unsigned int*)g,       \
                (__attribute__((address_space(3))) unsigned int*)lp, 16, 0, 0); \
        }                                                                       \
    }

    // A tile (128 rows x 128 k) in registers (L2-resident source)
    bfrag a[8][4];
    #pragma unroll
    for (int m = 0; m < 8; ++m) {
        const ushort* rp = zb + (size_t)(iBase + m * 16 + l15) * D;
        #pragma unroll
        for (int ks = 0; ks < 4; ++ks)
            a[m][ks] = *(const bfrag*)(rp + ks * 32 + lh * 8);
    }

    float rs[8][4];
    #pragma unroll
    for (int m = 0; m < 8; ++m)
        #pragma unroll
        for (int r = 0; r < 4; ++r) rs[m][r] = 0.0f;

    STAGE(&Bs[0][0], segBase);           // prologue: half 0
    __syncthreads();

    const int cB = w * 16 + l15;         // this lane's col within each half

    #pragma unroll 1
    for (int h = 0; h < HALVES; ++h) {
        const int jBase = segBase + h * 64;
        const ushort* bufc = &Bs[h & 1][0];

        // 1) LDS reads FIRST (no outstanding DMA -> no conservative vmcnt wait)
        bfrag b[4];
        #pragma unroll
        for (int ks = 0; ks < 4; ++ks) {
            const int k16 = ks * 4 + lh;
            const int slot = cB * 16 + (k16 ^ (cB & 7));
            b[ks] = *(const bfrag*)(bufc + slot * 8);
        }

        // 2) issue next half's DMA (latency covered by MFMA+exp below)
        if (h + 1 < HALVES) STAGE(&Bs[(h + 1) & 1][0], jBase + 64);

        // 3) compute
        f32x4 c[8];
        #pragma unroll
        for (int m = 0; m < 8; ++m) { f32x4 z4 = {0.f, 0.f, 0.f, 0.f}; c[m] = z4; }
        #pragma unroll
        for (int ks = 0; ks < 4; ++ks)
            #pragma unroll
            for (int m = 0; m < 8; ++m)
                c[m] = __builtin_amdgcn_mfma_f32_16x16x32_bf16(a[m][ks], b[ks], c[m], 0, 0, 0);

        if ((jBase & ~127) == iBase) {   // rare: half covers self-diagonal
            const int sOff = jBase - iBase;          // 0 or 64
            #pragma unroll
            for (int m = 0; m < 8; ++m)
                #pragma unroll
                for (int r = 0; r < 4; ++r) {
                    const int rowLocal = m * 16 + lh * 4 + r;
                    float e = fast_exp2(c[m][r]);
                    rs[m][r] += (rowLocal == sOff + cB) ? 0.0f : e;
                }
        } else {                         // hot path
            #pragma unroll
            for (int m = 0; m < 8; ++m)
                #pragma unroll
                for (int r = 0; r < 4; ++r)
                    rs[m][r] += fast_exp2(c[m][r]);
        }
        if ((jBase & ~127) == pBase) {   // rare: half covers partner diagonal
            const int pOff = jBase - pBase;          // 0 or 64
            #pragma unroll
            for (int m = 0; m < 8; ++m)
                #pragma unroll
                for (int r = 0; r < 4; ++r) {
                    const int rowLocal = m * 16 + lh * 4 + r;
                    if (rowLocal == pOff + cB)
                        posv[iBase + rowLocal] = c[m][r] * LN2;   // = 2*cos
                }
        }

        // 4) barrier (drains DMA vmcnt; next half's buffer is ready after this)
        __syncthreads();
    }
#undef STAGE

    // reduce rs over the 16 cols held across l15 lanes
    #pragma unroll
    for (int m = 0; m < 8; ++m)
        #pragma unroll
        for (int r = 0; r < 4; ++r) {
            float v = rs[m][r];
            v += __shfl_xor(v, 1); v += __shfl_xor(v, 2);
            v += __shfl_xor(v, 4); v += __shfl_xor(v, 8);
            rs[m][r] = v;
        }
    if (l15 == 0) {
        #pragma unroll
        for (int m = 0; m < 8; ++m)
            #pragma unroll
            for (int r = 0; r < 4; ++r)
                red[m * 16 + lh * 4 + r][w] = rs[m][r];
    }
    __syncthreads();
    if (t < 128) {
        float v = red[t][0] + red[t][1] + red[t][2] + red[t][3];
        partial[(size_t)seg * N_ROWS + iBase + t] = v;
    }
}

// ---------------- kernel 3: per-row loss + per-block deterministic sum ----------------
__global__ __launch_bounds__(256) void rowloss_kernel(
    const float* __restrict__ partial, const float* __restrict__ posv,
    float* __restrict__ bsum)
{
    const int row = blockIdx.x * 256 + threadIdx.x;
    float denom = 0.0f;
    #pragma unroll
    for (int s = 0; s < SEGS; ++s) denom += partial[(size_t)s * N_ROWS + row];
    float loss = logf(denom) - posv[row];
    #pragma unroll
    for (int m = 1; m < 64; m <<= 1) loss += __shfl_xor(loss, m);
    __shared__ float red[4];
    if ((threadIdx.x & 63) == 0) red[threadIdx.x >> 6] = loss;
    __syncthreads();
    if (threadIdx.x == 0) bsum[blockIdx.x] = red[0] + red[1] + red[2] + red[3];
}

// ---------------- kernel 4: final deterministic reduce of 32 block sums ----------------
__global__ __launch_bounds__(64) void final_reduce(
    const float* __restrict__ bsum, float* __restrict__ out)
{
    const int t = threadIdx.x;
    float s = (t < 32) ? bsum[t] : 0.0f;
    #pragma unroll
    for (int m = 1; m < 64; m <<= 1) s += __shfl_xor(s, m);
    if (t == 0) out[0] = s * (1.0f / (float)N_ROWS);
}

extern "C" void kernel_launch(void* const* d_in, const int* in_sizes, int n_in,
                              void* d_out, int out_size, void* d_ws, size_t ws_size,
                              hipStream_t stream) {
    const float* proj1 = (const float*)d_in[0];
    const float* proj2 = (const float*)d_in[1];
    float* out = (float*)d_out;

    char* ws = (char*)d_ws;
    ushort* zb      = (ushort*)ws;                                      // 2 MB
    float*  partial = (float*)(ws + (size_t)2 * 1024 * 1024);           // 256 KB
    float*  posv    = (float*)(ws + (size_t)2 * 1024 * 1024 + 512 * 1024);   // 32 KB
    float*  bsum    = (float*)(ws + (size_t)2 * 1024 * 1024 + 768 * 1024);   // 128 B

    normalize_kernel<<<N_ROWS / 4, 256, 0, stream>>>(proj1, proj2, zb);
    simloss_mfma<<<IBLKS * SEGS, 256, 0, stream>>>(zb, partial, posv);
    rowloss_kernel<<<N_ROWS / 256, 256, 0, stream>>>(partial, posv, bsum);
    final_reduce<<<1, 64, 0, stream>>>(bsum, out);
}